// Round 10
// baseline (88.970 us; speedup 1.0000x reference)
//
#include <hip/hip_runtime.h>
#include <hip/hip_bf16.h>

// KAN layer: out[n,i] = sum_{g,d} splines[i,g,d] * relu(1 - |x[n,d] - grid[g]|)
// B=8192, D=192, G=192, O=16.
//
// x,grid in [0,1] => relu is identity. Piecewise-linear in x per d:
//   sum_g s*(1-|x-r_g|) = Cp(g*) - x*A(g*),  g* = floor(x*191)
// A = 2P - T, Cp = T - U + 2Q; P,Q inclusive prefix sums of s and s*grid
// over g. tab[d][g][i] = u32 {lo=bf16(A), hi=bf16(Cp)} (2.36 MB, in d_ws).
//
// R9 lesson: work is only ~8.5us; ~15us is dispatch overhead (2 dispatches
// + base). R10: ONE dispatch, producer/consumer handshake in-kernel:
//  - blocks 0..767: R4 pre (4 (d,i)-pair waves); threadfence; slot=MAGIC.
//  - blocks 768..2815: 4 n-rows each; prefetch x + g-indices; poll slots
//    (agent-scope); acquire-fence ONLY if waited; gather+fold+store.
//  - deadlock-proof: bounded spin then consumer produces missing slots
//    itself (duplicate identical writes = benign).
//  - replay-safe: tab is a pure function of inputs and fully rewritten
//    every launch; leftover MAGIC just skips the wait (values identical).
//    Poison 0xAA != MAGIC -> normal wait path.

#define Dn 192
#define Gn 192
#define On 16
#define Bn 8192

#define NPRE 768                 // producer blocks; 4 (d,i) pairs each = 3072
#define NCON (Bn / 4)            // 2048 consumer blocks; 4 n each
#define NBLK (NPRE + NCON)       // 2816
#define MAGIC 0x5A17C0DEu
#define SPIN_LIMIT 512           // ~0.3ms before self-rescue (never in practice)

__device__ __forceinline__ unsigned short f2bf(float f) {
    union { float f; unsigned u; } v; v.f = f;
    unsigned r = v.u + 0x7FFF + ((v.u >> 16) & 1);   // RTN-even
    return (unsigned short)(r >> 16);
}

// one (d,i) pair per wave — R4-exact pre body
__device__ __forceinline__ void pre_pair(int w, int lane,
                                         const float* __restrict__ sp,
                                         const float* __restrict__ grid,
                                         unsigned* __restrict__ tab) {
    int d = w >> 4;
    int i = w & 15;

    int g0 = lane * 3;  // 192 = 64 lanes * 3 g's each
    const float* s_base = sp + (size_t)i * Gn * Dn + d;   // splines[i,g,d]
    float s0 = s_base[(size_t)(g0 + 0) * Dn];
    float s1 = s_base[(size_t)(g0 + 1) * Dn];
    float s2 = s_base[(size_t)(g0 + 2) * Dn];
    float q0 = s0 * grid[g0 + 0];
    float q1 = s1 * grid[g0 + 1];
    float q2 = s2 * grid[g0 + 2];

    float lp1 = s0 + s1, lp2 = lp1 + s2;
    float lq1 = q0 + q1, lq2 = lq1 + q2;
    float sP = lp2, sQ = lq2;
    #pragma unroll
    for (int off = 1; off < 64; off <<= 1) {
        float pP = __shfl_up(sP, off);
        float pQ = __shfl_up(sQ, off);
        if (lane >= off) { sP += pP; sQ += pQ; }
    }
    float exP = sP - lp2, exQ = sQ - lq2;
    float T = __shfl(sP, 63);
    float U = __shfl(sQ, 63);

    float P[3] = { exP + s0, exP + lp1, exP + lp2 };
    float Q[3] = { exQ + q0, exQ + lq1, exQ + lq2 };

    #pragma unroll
    for (int k = 0; k < 3; ++k) {
        int g = g0 + k;
        float A  = 2.0f * P[k] - T;
        float Cp = T - U + 2.0f * Q[k];
        tab[((size_t)d * Gn + g) * On + i] = (unsigned)f2bf(A) | ((unsigned)f2bf(Cp) << 16);
    }
}

__global__ __launch_bounds__(256) void kan_one(const float* __restrict__ x,
                                               const float* __restrict__ sp,
                                               const float* __restrict__ grid,
                                               unsigned* __restrict__ tab,
                                               unsigned* __restrict__ slots,
                                               float* __restrict__ out) {
    int t = threadIdx.x;
    int lane = t & 63;
    int wv = t >> 6;
    unsigned b = blockIdx.x;

    if (b < NPRE) {
        // ---------------- producer ----------------
        pre_pair((int)b * 4 + wv, lane, sp, grid, tab);
        __syncthreads();                       // all 4 waves' stores issued
        if (t == 0) {
            __threadfence();                   // device-scope release (wb L2)
            __hip_atomic_store(&slots[b], MAGIC, __ATOMIC_RELEASE,
                               __HIP_MEMORY_SCOPE_AGENT);
        }
        return;
    }

    // ---------------- consumer: wave = one n ----------------
    int n = ((int)b - NPRE) * 4 + wv;
    int i = lane & 15;
    int q = lane >> 4;                         // d-quarter 0..3

    // prefetch x row-quarter and precompute packed g-indices
    const float4* xr = (const float4*)(x + (size_t)n * Dn + q * 48);
    float vx[48];
    unsigned pg[12];
    #pragma unroll
    for (int j = 0; j < 12; ++j) {
        float4 v4 = xr[j];
        float vv[4] = { v4.x, v4.y, v4.z, v4.w };
        unsigned pk = 0;
        #pragma unroll
        for (int k = 0; k < 4; ++k) {
            float v = vv[k];
            int g = (int)(v * 191.0f);
            g = (g < 0) ? 0 : (g > 191 ? 191 : g);
            vx[j * 4 + k] = v;
            pk |= ((unsigned)g) << (8 * k);
        }
        pg[j] = pk;
    }

    // wait for producers (skip entirely when slots already MAGIC)
    bool waited = false;
    {
        int rounds = 0;
        for (;;) {
            bool ok = true;
            #pragma unroll
            for (int j = 0; j < NPRE / 64; ++j) {    // 12 slots per lane
                unsigned v = __hip_atomic_load(&slots[lane + 64 * j],
                                               __ATOMIC_RELAXED,
                                               __HIP_MEMORY_SCOPE_AGENT);
                ok &= (v == MAGIC);
            }
            if (__all(ok)) break;
            waited = true;
            if (++rounds > SPIN_LIMIT) {
                // rescue: produce missing slots ourselves (value-identical
                // duplicate writes are benign) -> no deadlock for any
                // block-dispatch order.
                for (int m = 0; m < NPRE; ++m) {
                    unsigned v = __hip_atomic_load(&slots[m], __ATOMIC_RELAXED,
                                                   __HIP_MEMORY_SCOPE_AGENT);
                    if (v != MAGIC) {
                        #pragma unroll
                        for (int p = 0; p < 4; ++p)
                            pre_pair(m * 4 + p, lane, sp, grid, tab);
                        __threadfence();
                        if (lane == 0)
                            __hip_atomic_store(&slots[m], MAGIC, __ATOMIC_RELEASE,
                                               __HIP_MEMORY_SCOPE_AGENT);
                    }
                }
                break;
            }
            __builtin_amdgcn_s_sleep(8);
        }
    }
    if (waited) __threadfence();   // acquire side: invalidate L1/L2 before tab reads

    // gather + accumulate: 48 d's per lane
    const unsigned* tb = tab + i;
    float acc = 0.0f;
    #pragma unroll
    for (int j = 0; j < 12; ++j) {
        unsigned pk = pg[j];
        #pragma unroll
        for (int k = 0; k < 4; ++k) {
            int dd = j * 4 + k;
            int g = (int)((pk >> (8 * k)) & 0xFFu);
            unsigned e = tb[(((q * 48 + dd) * Gn) + g) * On];
            union { unsigned u; float f; } A, C;
            A.u = e << 16;              // bf16 lo -> f32
            C.u = e & 0xFFFF0000u;      // bf16 hi -> f32
            acc += C.f;
            acc = fmaf(-vx[dd], A.f, acc);   // acc += Cp - x*A
        }
    }
    // fold the 4 d-quarters (lane bits 4,5)
    acc += __shfl_xor(acc, 16);
    acc += __shfl_xor(acc, 32);
    if (lane < 16) out[(size_t)n * On + i] = acc;
}

// ---------------- fallback (ws too small): direct computation ------------
__global__ __launch_bounds__(256) void kan_naive(const float* __restrict__ x,
                                                 const float* __restrict__ sp,
                                                 const float* __restrict__ grid,
                                                 float* __restrict__ out) {
    __shared__ float xs[Dn];
    __shared__ float gsh[Gn];
    __shared__ float red[4];
    int n = blockIdx.x;
    int t = threadIdx.x;
    if (t < Dn) { xs[t] = x[(size_t)n * Dn + t]; gsh[t] = grid[t]; }
    __syncthreads();
    float acc[On];
    #pragma unroll
    for (int i = 0; i < On; ++i) acc[i] = 0.0f;
    for (int idx = t; idx < Gn * Dn; idx += 256) {
        int g = idx / Dn;
        int d = idx - g * Dn;
        float b = fmaxf(0.0f, 1.0f - fabsf(xs[d] - gsh[g]));
        #pragma unroll
        for (int i = 0; i < On; ++i)
            acc[i] += sp[(size_t)i * Gn * Dn + idx] * b;
    }
    for (int i = 0; i < On; ++i) {
        float v = acc[i];
        #pragma unroll
        for (int off = 32; off > 0; off >>= 1) v += __shfl_down(v, off);
        if ((t & 63) == 0) red[t >> 6] = v;
        __syncthreads();
        if (t == 0) out[(size_t)n * On + i] = red[0] + red[1] + red[2] + red[3];
        __syncthreads();
    }
}

extern "C" void kernel_launch(void* const* d_in, const int* in_sizes, int n_in,
                              void* d_out, int out_size, void* d_ws, size_t ws_size,
                              hipStream_t stream) {
    const float* x    = (const float*)d_in[0];
    const float* sp   = (const float*)d_in[1];
    const float* grid = (const float*)d_in[2];
    float* out = (float*)d_out;

    const size_t TAB_BYTES  = (size_t)Dn * Gn * On * sizeof(unsigned);  // 2.36 MB
    const size_t SLOT_BYTES = (size_t)NPRE * sizeof(unsigned);          // 3 KB
    if (ws_size >= TAB_BYTES + SLOT_BYTES) {
        unsigned* tab   = (unsigned*)d_ws;
        unsigned* slots = (unsigned*)((char*)d_ws + TAB_BYTES);
        kan_one<<<NBLK, 256, 0, stream>>>(x, sp, grid, tab, slots, out);
    } else {
        kan_naive<<<Bn, 256, 0, stream>>>(x, sp, grid, out);
    }
}

// Round 11
// 22.125 us; speedup vs baseline: 4.0212x; 4.0212x over previous
//
#include <hip/hip_runtime.h>
#include <hip/hip_bf16.h>

// KAN layer: out[n,i] = sum_{g,d} splines[i,g,d] * relu(1 - |x[n,d] - grid[g]|)
// B=8192, D=192, G=192, O=16.
//
// x,grid in [0,1] => relu is identity. Piecewise-linear in x per d:
//   sum_g s*(1-|x-r_g|) = Cp(g*) - x*A(g*),  g* = floor(x*191)
// A = 2P - T, Cp = T - U + 2Q; P,Q inclusive prefix sums of s and s*grid
// over g. tab[d][g][i] = u32 {lo=bf16(A), hi=bf16(Cp)} (2.36 MB in d_ws);
// main = one 64B-line L2 gather + ~4 VALU per (n,d) for all 16 i.
//
// R10 lessons: ALL cross-block signaling is broken-slow on gfx950
// (grid.sync ~150us; agent-scope flag polling reads stale L2 ~130us).
// Two plain dispatches. Budget: ~10.7us fixed harness overhead,
// main ~8.5-9us (L2 random-line rate ~12TB/s), pre ~2.5us.
// R11 change (single variable vs R4 champion): pre waves cover a d-PAIR
// with float2 loads -> pre load-requests halved (590K -> 295K).

#define Dn 192
#define Gn 192
#define On 16
#define Bn 8192

#define DSPLIT 8
#define DCHUNK (Dn / DSPLIT)    // 24

__device__ __forceinline__ unsigned short f2bf(float f) {
    union { float f; unsigned u; } v; v.f = f;
    unsigned r = v.u + 0x7FFF + ((v.u >> 16) & 1);   // RTN-even
    return (unsigned short)(r >> 16);
}

// ---------------- precompute: one wave per (d-pair, i) --------------------
// 384 blocks x 256 thr = 1536 waves. Lane handles 3 g's x 2 d's (float2
// loads, 8B-aligned since d is even). Also zeroes out[] for main's atomics.
__global__ __launch_bounds__(256) void kan_pre(const float* __restrict__ sp,
                                               const float* __restrict__ grid,
                                               unsigned* __restrict__ tab,
                                               float* __restrict__ out) {
    int gtid = blockIdx.x * blockDim.x + threadIdx.x;
    if (gtid < Bn * On / 4)                     // 32768 float4 = 131072 floats
        ((float4*)out)[gtid] = make_float4(0.f, 0.f, 0.f, 0.f);

    int w = gtid >> 6;              // wave id, 0..1535 (no tail)
    int lane = threadIdx.x & 63;
    int dp = w >> 4;                // d-pair 0..95
    int i  = w & 15;
    int d  = dp * 2;

    int g0 = lane * 3;              // 192 = 64 lanes * 3 g's each
    const float* s_base = sp + (size_t)i * Gn * Dn + d;   // splines[i,g,d]
    // float2 covers (d, d+1) for each of this lane's 3 g's
    float2 s0 = *(const float2*)&s_base[(size_t)(g0 + 0) * Dn];
    float2 s1 = *(const float2*)&s_base[(size_t)(g0 + 1) * Dn];
    float2 s2 = *(const float2*)&s_base[(size_t)(g0 + 2) * Dn];
    float r0 = grid[g0 + 0], r1 = grid[g0 + 1], r2 = grid[g0 + 2];

    #pragma unroll
    for (int j = 0; j < 2; ++j) {   // the two d's of the pair
        float v0 = (j == 0) ? s0.x : s0.y;
        float v1 = (j == 0) ? s1.x : s1.y;
        float v2 = (j == 0) ? s2.x : s2.y;
        float q0 = v0 * r0, q1 = v1 * r1, q2 = v2 * r2;

        float lp1 = v0 + v1, lp2 = lp1 + v2;   // local inclusive prefix of P
        float lq1 = q0 + q1, lq2 = lq1 + q2;   // local inclusive prefix of Q
        float sP = lp2, sQ = lq2;
        #pragma unroll
        for (int off = 1; off < 64; off <<= 1) {
            float pP = __shfl_up(sP, off);
            float pQ = __shfl_up(sQ, off);
            if (lane >= off) { sP += pP; sQ += pQ; }
        }
        float exP = sP - lp2, exQ = sQ - lq2;  // exclusive carry
        float T = __shfl(sP, 63);
        float U = __shfl(sQ, 63);

        float P[3] = { exP + v0, exP + lp1, exP + lp2 };
        float Q[3] = { exQ + q0, exQ + lq1, exQ + lq2 };

        #pragma unroll
        for (int k = 0; k < 3; ++k) {
            int g = g0 + k;
            float A  = 2.0f * P[k] - T;
            float Cp = T - U + 2.0f * Q[k];
            tab[((size_t)(d + j) * Gn + g) * On + i] =
                (unsigned)f2bf(A) | ((unsigned)f2bf(Cp) << 16);
        }
    }
}

// ---------------- main (R4-exact): thread = (i, n), d-chunk = bid&7 ------
__global__ __launch_bounds__(256) void kan_main(const float* __restrict__ x,
                                                const unsigned* __restrict__ tab,
                                                float* __restrict__ out) {
    int t = threadIdx.x;
    int i  = t & 15;
    int nn = t >> 4;                        // 0..15
    unsigned bid = blockIdx.x;              // 4096 blocks
    int chunk = bid & 7;                    // d-chunk == XCD under round-robin
    int n = (bid >> 3) * 16 + nn;
    int d0 = chunk * DCHUNK;

    const float4* xr = (const float4*)(x + (size_t)n * Dn + d0);  // 6 float4
    const unsigned* tb = tab + (size_t)d0 * Gn * On + i;

    float acc = 0.0f;
    #pragma unroll
    for (int d4 = 0; d4 < DCHUNK / 4; ++d4) {   // 6 iterations
        float4 xv = xr[d4];
        float vx[4] = { xv.x, xv.y, xv.z, xv.w };
        #pragma unroll
        for (int k = 0; k < 4; ++k) {
            float v = vx[k];
            int g = (int)(v * 191.0f);
            g = (g < 0) ? 0 : (g > 191 ? 191 : g);
            unsigned e = tb[((d4 * 4 + k) * Gn + g) * On];
            union { unsigned u; float f; } A, C;
            A.u = e << 16;            // bf16 lo -> f32
            C.u = e & 0xFFFF0000u;    // bf16 hi -> f32
            acc += C.f;
            acc = fmaf(-v, A.f, acc); // acc += Cp - x*A
        }
    }
    atomicAdd(&out[(size_t)n * On + i], acc);
}

// ---------------- fallback (ws too small): direct computation ------------
__global__ __launch_bounds__(256) void kan_naive(const float* __restrict__ x,
                                                 const float* __restrict__ sp,
                                                 const float* __restrict__ grid,
                                                 float* __restrict__ out) {
    __shared__ float xs[Dn];
    __shared__ float gsh[Gn];
    __shared__ float red[4];
    int n = blockIdx.x;
    int t = threadIdx.x;
    if (t < Dn) { xs[t] = x[(size_t)n * Dn + t]; gsh[t] = grid[t]; }
    __syncthreads();
    float acc[On];
    #pragma unroll
    for (int i = 0; i < On; ++i) acc[i] = 0.0f;
    for (int idx = t; idx < Gn * Dn; idx += 256) {
        int g = idx / Dn;
        int d = idx - g * Dn;
        float b = fmaxf(0.0f, 1.0f - fabsf(xs[d] - gsh[g]));
        #pragma unroll
        for (int i = 0; i < On; ++i)
            acc[i] += sp[(size_t)i * Gn * Dn + idx] * b;
    }
    for (int i = 0; i < On; ++i) {
        float v = acc[i];
        #pragma unroll
        for (int off = 32; off > 0; off >>= 1) v += __shfl_down(v, off);
        if ((t & 63) == 0) red[t >> 6] = v;
        __syncthreads();
        if (t == 0) out[(size_t)n * On + i] = red[0] + red[1] + red[2] + red[3];
        __syncthreads();
    }
}

extern "C" void kernel_launch(void* const* d_in, const int* in_sizes, int n_in,
                              void* d_out, int out_size, void* d_ws, size_t ws_size,
                              hipStream_t stream) {
    const float* x    = (const float*)d_in[0];
    const float* sp   = (const float*)d_in[1];
    const float* grid = (const float*)d_in[2];
    float* out = (float*)d_out;

    const size_t TAB_BYTES = (size_t)Dn * Gn * On * sizeof(unsigned);  // 2.36 MB
    if (ws_size >= TAB_BYTES) {
        unsigned* tab = (unsigned*)d_ws;
        kan_pre<<<384, 256, 0, stream>>>(sp, grid, tab, out);           // 1536 waves
        kan_main<<<(Bn / 16) * DSPLIT, 256, 0, stream>>>(x, tab, out);  // 4096 blocks
    } else {
        kan_naive<<<Bn, 256, 0, stream>>>(x, sp, grid, out);
    }
}